// Round 1
// 655.753 us; speedup vs baseline: 1.1773x; 1.1773x over previous
//
#include <hip/hip_runtime.h>
#include <stdint.h>

#define B_N 131072
#define IN_DIM 256

typedef __attribute__((ext_vector_type(8))) short bhalf8;   // 8 x bf16 (4 VGPRs)
typedef __attribute__((ext_vector_type(4))) float f32x4;

// ---- constexpr problem tables ----
// ent codes: 0=contributor(c), 1=repository(r), 2=pr(p)
// task0: [c,r]  task1: [r,p,c]  task2: [r,c]  task3: [c,c]
__device__ constexpr int kW1Off[4] = {49152, 114688, 212992, 278528}; // bf16 elem offsets
#define W2_OFF 344064
#define PREP_TOTAL 606208

__device__ __forceinline__ short f2bf(float x) {
    unsigned u = __float_as_uint(x);
    unsigned r = (u + 0x7fffu + ((u >> 16) & 1u)) >> 16;
    return (short)r;
}

// ================= prep: zero counters + convert weights to bf16 =================
struct PrepParams {
    const float* src[11];
    short* dst;
    int* cnt;
};

__global__ void prep_kernel(PrepParams P) {
    const int seg[11] = {16384,16384,16384, 65536,98304,65536,65536, 65536,65536,65536,65536};
    int g = blockIdx.x * blockDim.x + threadIdx.x;
    if (g < 4) P.cnt[g] = 0;
    const int stride = gridDim.x * blockDim.x;
    for (int i = g; i < PREP_TOTAL; i += stride) {
        int s = 0, base = 0;
        #pragma unroll
        for (int k = 0; k < 10; ++k) {
            if (i >= base + seg[k]) { base += seg[k]; s = k + 1; }
        }
        P.dst[i] = f2bf(P.src[s][i - base]);
    }
}

// ================= partition: bucket samples by task (block-aggregated atomics) =================
__global__ __launch_bounds__(1024)
void partition_kernel(const float* __restrict__ oh, int* cnt, int* lists) {
    __shared__ int sCnt[4];
    __shared__ int sWOff[16][4];
    __shared__ int sBase[4];
    const int tid  = threadIdx.x;
    const int wave = tid >> 6;
    const int lane = tid & 63;
    const int i = blockIdx.x * 1024 + tid;     // B_N == 128*1024 exactly

    f32x4 v = *(const f32x4*)(oh + 4 * (size_t)i);
    int t = 0; float best = v.x;
    if (v.y > best) { best = v.y; t = 1; }
    if (v.z > best) { best = v.z; t = 2; }
    if (v.w > best) { best = v.w; t = 3; }

    if (tid < 4) sCnt[tid] = 0;
    __syncthreads();
    #pragma unroll
    for (int tt = 0; tt < 4; ++tt) {
        unsigned long long mk = __ballot(t == tt);
        if (lane == 0) sWOff[wave][tt] = mk ? atomicAdd(&sCnt[tt], __popcll(mk)) : 0;
    }
    __syncthreads();
    if (tid < 4) sBase[tid] = atomicAdd(&cnt[tid], sCnt[tid]);   // 4 global atomics / block
    __syncthreads();
    #pragma unroll
    for (int tt = 0; tt < 4; ++tt) {
        unsigned long long mk = __ballot(t == tt);
        if (t == tt) {
            int pos = sBase[tt] + sWOff[wave][tt] + __popcll(mk & ((1ull << lane) - 1ull));
            lists[tt * B_N + pos] = i;
        }
    }
}

// ================= fused per-task MLP =================
struct MlpParams {
    const float* xs[3];    // c_x, r_x, p_x
    const float* bes[3];   // b_c, b_r, b_p
    const float* b1[4];
    const float* b2[4];
    const float* b3[4];
    const float* w3f[4];   // fp32 w3 [1,128]
    const short* bf;       // bf16 weights base in ws
    const int* cnt;
    const int* lists;
    float* out;
};

#define PA  200   // sA pitch (elems): max din 192 + 8 -> 100 dw stride (==4 mod 32)
#define PHC 136   // sH chunk pitch: 128 + 8 -> 68 dw stride (==4 mod 32)

template<int TASK>
__device__ __forceinline__ void mlp_body(const MlpParams& P, short* sA, short* sH,
                                         int* sIdx, float* sRed, int m_count, int tile0) {
    constexpr int NS  = (TASK == 1) ? 3 : 2;
    constexpr int DIN = 64 * NS;
    constexpr int KS1 = DIN / 32;
    constexpr int SL0 = (TASK == 0) ? 0 : (TASK == 1) ? 1 : (TASK == 2) ? 1 : 0;
    constexpr int SL1 = (TASK == 0) ? 1 : (TASK == 1) ? 2 : (TASK == 2) ? 0 : 0;
    constexpr int SL2 = 0; // only task1 (contributor)
    constexpr int NUNITS = (TASK == 3) ? 4 : NS * 4;   // task3: both slots identical -> compute once

    const int tid  = threadIdx.x;
    const int wave = tid >> 6;
    const int lane = tid & 63;
    const int quad = lane >> 4;
    const int l16  = lane & 15;

    // ---- load tile sample indices ----
    if (tid < 64) {
        int gp = tile0 + tid;
        int cl = gp < m_count ? gp : (m_count - 1);
        sIdx[tid] = P.lists[TASK * B_N + cl];
    }
    __syncthreads();

    // ---- Phase B: embeddings -> sA (A-matrix [64, DIN] bf16) ----
    #pragma unroll
    for (int pass = 0; pass < (NUNITS + 7) / 8; ++pass) {
        int u = wave + pass * 8;
        if (u < NUNITS) {
            const int slot = u >> 2;
            const int mt   = u & 3;
            const int ent  = (slot == 0) ? SL0 : (slot == 1) ? SL1 : SL2;
            const float* xrow = P.xs[ent] + (size_t)sIdx[mt * 16 + l16] * IN_DIM;
            const float* be   = P.bes[ent];
            const short* we   = P.bf + ent * 16384;

            bhalf8 af[8];
            #pragma unroll
            for (int ks = 0; ks < 8; ++ks) {
                const int k0 = ks * 32 + quad * 8;
                f32x4 x0 = *(const f32x4*)(xrow + k0);
                f32x4 x1 = *(const f32x4*)(xrow + k0 + 4);
                bhalf8 f;
                f[0] = f2bf(x0.x); f[1] = f2bf(x0.y); f[2] = f2bf(x0.z); f[3] = f2bf(x0.w);
                f[4] = f2bf(x1.x); f[5] = f2bf(x1.y); f[6] = f2bf(x1.z); f[7] = f2bf(x1.w);
                af[ks] = f;
            }
            #pragma unroll
            for (int nt = 0; nt < 4; ++nt) {
                const int n = nt * 16 + l16;          // 0..63
                f32x4 acc = {0.f, 0.f, 0.f, 0.f};
                #pragma unroll
                for (int ks = 0; ks < 8; ++ks) {
                    bhalf8 bv = *(const bhalf8*)(we + n * 256 + ks * 32 + quad * 8);
                    acc = __builtin_amdgcn_mfma_f32_16x16x32_bf16(af[ks], bv, acc, 0, 0, 0);
                }
                const float bias = be[n];
                #pragma unroll
                for (int r = 0; r < 4; ++r) {
                    const short val = f2bf(acc[r] + bias);
                    const int row = mt * 16 + quad * 4 + r;
                    sA[row * PA + slot * 64 + n] = val;
                    if (TASK == 3) sA[row * PA + 64 + n] = val;   // duplicate slot1 = slot0
                }
            }
        }
    }
    __syncthreads();

    // ---- Phases C+D fused: h1 chunked (4 x 128 cols), double-buffered in sH ----
    // h2 = sum_chunks relu(h1_chunk) @ W2_chunk^T  (relu is elementwise -> K chunks legal)
    const short* w1 = P.bf + kW1Off[TASK];
    const float* b1 = P.b1[TASK];
    const short* w2 = P.bf + W2_OFF + TASK * 65536;
    const int mt4 = wave & 3;     // D: wave's 16-row group
    const int nh  = wave >> 2;    // D: wave's 64-col half of h2

    f32x4 acc2[4];
    #pragma unroll
    for (int ntl = 0; ntl < 4; ++ntl) acc2[ntl] = {0.f, 0.f, 0.f, 0.f};

    #pragma unroll
    for (int cc = 0; cc <= 4; ++cc) {
        // consume-side LDS reads first (previous chunk, other buffer) to overlap with produce
        bhalf8 a2[4];
        if (cc >= 1) {
            const short* hb = sH + ((cc - 1) & 1) * (64 * PHC);
            #pragma unroll
            for (int ks = 0; ks < 4; ++ks)
                a2[ks] = *(const bhalf8*)(hb + (mt4 * 16 + l16) * PHC + ks * 32 + quad * 8);
        }
        // produce chunk cc of h1 into sH[cc&1]: each wave computes 16 of the 128 cols
        if (cc < 4) {
            short* hb = sH + (cc & 1) * (64 * PHC);
            const int nl = wave * 16 + l16;        // 0..127 within chunk
            const int n  = cc * 128 + nl;          // 0..511 global h1 col
            f32x4 acc1[4];
            #pragma unroll
            for (int mt = 0; mt < 4; ++mt) acc1[mt] = {0.f, 0.f, 0.f, 0.f};
            #pragma unroll
            for (int ks = 0; ks < KS1; ++ks) {
                bhalf8 bv = *(const bhalf8*)(w1 + n * DIN + ks * 32 + quad * 8);
                #pragma unroll
                for (int mt = 0; mt < 4; ++mt) {
                    bhalf8 av = *(const bhalf8*)(sA + (mt * 16 + l16) * PA + ks * 32 + quad * 8);
                    acc1[mt] = __builtin_amdgcn_mfma_f32_16x16x32_bf16(av, bv, acc1[mt], 0, 0, 0);
                }
            }
            const float bias = b1[n];
            #pragma unroll
            for (int mt = 0; mt < 4; ++mt)
                #pragma unroll
                for (int r = 0; r < 4; ++r) {
                    float v = acc1[mt][r] + bias;
                    v = v > 0.f ? v : 0.f;
                    hb[(mt * 16 + quad * 4 + r) * PHC + nl] = f2bf(v);
                }
        }
        // consume chunk cc-1: accumulate h2 partial (K=128)
        if (cc >= 1) {
            const int c0 = (cc - 1) * 128;
            #pragma unroll
            for (int ntl = 0; ntl < 4; ++ntl) {
                const int n2 = (nh * 4 + ntl) * 16 + l16;   // 0..127
                #pragma unroll
                for (int ks = 0; ks < 4; ++ks) {
                    bhalf8 bv = *(const bhalf8*)(w2 + n2 * 512 + c0 + ks * 32 + quad * 8);
                    acc2[ntl] = __builtin_amdgcn_mfma_f32_16x16x32_bf16(a2[ks], bv, acc2[ntl], 0, 0, 0);
                }
            }
        }
        __syncthreads();
    }

    // ---- epilogue: bias + relu + dot(w3), cross-lane reduce ----
    {
        const float* b2 = P.b2[TASK];
        const float* w3 = P.w3f[TASK];
        float s0 = 0.f, s1 = 0.f, s2 = 0.f, s3 = 0.f;
        #pragma unroll
        for (int ntl = 0; ntl < 4; ++ntl) {
            const int n2 = (nh * 4 + ntl) * 16 + l16;
            const float bias = b2[n2];
            const float wv = w3[n2];
            float h;
            h = acc2[ntl][0] + bias; h = h > 0.f ? h : 0.f; s0 += h * wv;
            h = acc2[ntl][1] + bias; h = h > 0.f ? h : 0.f; s1 += h * wv;
            h = acc2[ntl][2] + bias; h = h > 0.f ? h : 0.f; s2 += h * wv;
            h = acc2[ntl][3] + bias; h = h > 0.f ? h : 0.f; s3 += h * wv;
        }
        #pragma unroll
        for (int m = 1; m < 16; m <<= 1) {
            s0 += __shfl_xor(s0, m);
            s1 += __shfl_xor(s1, m);
            s2 += __shfl_xor(s2, m);
            s3 += __shfl_xor(s3, m);
        }
        if (l16 == 0) {
            const int rbase = mt4 * 16 + quad * 4;
            sRed[(rbase + 0) * 2 + nh] = s0;
            sRed[(rbase + 1) * 2 + nh] = s1;
            sRed[(rbase + 2) * 2 + nh] = s2;
            sRed[(rbase + 3) * 2 + nh] = s3;
        }
    }
    __syncthreads();

    // ---- sigmoid + scatter ----
    if (tid < 64) {
        int gp = tile0 + tid;
        if (gp < m_count) {
            float z = sRed[tid * 2] + sRed[tid * 2 + 1] + P.b3[TASK][0];
            float o = 1.0f / (1.0f + expf(-z));
            P.out[sIdx[tid]] = o;
        }
    }
}

__global__ __launch_bounds__(512, 4)
void mlp_kernel(MlpParams P) {
    __shared__ short sA[64 * PA];          // 25.6 KB
    __shared__ short sH[2 * 64 * PHC];     // 34.8 KB (double-buffered 128-col chunks)
    __shared__ int   sIdx[64];
    __shared__ float sRed[128];

    const int task  = blockIdx.y;
    const int tile0 = blockIdx.x * 64;
    const int m_count = P.cnt[task];
    if (tile0 >= m_count) return;

    switch (task) {
        case 0: mlp_body<0>(P, sA, sH, sIdx, sRed, m_count, tile0); break;
        case 1: mlp_body<1>(P, sA, sH, sIdx, sRed, m_count, tile0); break;
        case 2: mlp_body<2>(P, sA, sH, sIdx, sRed, m_count, tile0); break;
        default: mlp_body<3>(P, sA, sH, sIdx, sRed, m_count, tile0); break;
    }
}

// ================= host =================
extern "C" void kernel_launch(void* const* d_in, const int* in_sizes, int n_in,
                              void* d_out, int out_size, void* d_ws, size_t ws_size,
                              hipStream_t stream) {
    // ws layout
    int*   cnt   = (int*)d_ws;
    int*   lists = (int*)((char*)d_ws + 64);
    short* bf    = (short*)((char*)d_ws + 64 + (size_t)4 * B_N * 4);

    // prep: convert weights to bf16, zero counters
    PrepParams pp;
    pp.src[0]  = (const float*)d_in[5];   // w_c
    pp.src[1]  = (const float*)d_in[7];   // w_r
    pp.src[2]  = (const float*)d_in[9];   // w_p
    pp.src[3]  = (const float*)d_in[13];  // w1_0
    pp.src[4]  = (const float*)d_in[19];  // w1_1
    pp.src[5]  = (const float*)d_in[25];  // w1_2
    pp.src[6]  = (const float*)d_in[31];  // w1_3
    pp.src[7]  = (const float*)d_in[15];  // w2_0
    pp.src[8]  = (const float*)d_in[21];  // w2_1
    pp.src[9]  = (const float*)d_in[27];  // w2_2
    pp.src[10] = (const float*)d_in[33];  // w2_3
    pp.dst = bf;
    pp.cnt = cnt;
    prep_kernel<<<512, 256, 0, stream>>>(pp);

    partition_kernel<<<B_N / 1024, 1024, 0, stream>>>((const float*)d_in[0], cnt, lists);

    MlpParams mp;
    mp.xs[0]  = (const float*)d_in[1];    // c_x
    mp.xs[1]  = (const float*)d_in[2];    // r_x
    mp.xs[2]  = (const float*)d_in[3];    // p_x
    mp.bes[0] = (const float*)d_in[6];
    mp.bes[1] = (const float*)d_in[8];
    mp.bes[2] = (const float*)d_in[10];
    for (int t = 0; t < 4; ++t) {
        mp.b1[t]  = (const float*)d_in[14 + 6 * t];
        mp.b2[t]  = (const float*)d_in[16 + 6 * t];
        mp.w3f[t] = (const float*)d_in[17 + 6 * t];
        mp.b3[t]  = (const float*)d_in[18 + 6 * t];
    }
    mp.bf    = bf;
    mp.cnt   = cnt;
    mp.lists = lists;
    mp.out   = (float*)d_out;

    mlp_kernel<<<dim3((B_N + 63) / 64, 4), 512, 0, stream>>>(mp);
}